// Round 1
// baseline (2428.094 us; speedup 1.0000x reference)
//
#include <hip/hip_runtime.h>

// CANPathIntegrator — R6: 2-D (batch-group x row-slice) decomposition.
// R5 used 128 blocks on 256 CUs (Occupancy 23%) and re-streamed all of A
// (1 MB) from L2 every step per block. Now: 256 blocks = 32 groups of 16
// batches x 8 row-slices of 64 A-rows. Each block streams only its 128 KB
// A slice per step (slice s lands on XCD s via blockIdx%8 -> slice stays
// L2-resident), computes w-rows for 16 batches (16x A reuse per element),
// and exchanges only the per-batch 2-float dx_can partial via d_ws with an
// 8-block agent-scope barrier (1 per step, double-buffered partials).
// x/zx are recomputed redundantly per group (bitwise identical across the
// 8 slice blocks). LDS padded >80 KB -> exactly 1 block/CU, grid == #CUs,
// so all blocks co-resident and the spin barrier cannot deadlock.

namespace {
constexpr int NT   = 128;   // time steps
constexpr int D    = 512;
constexpr int KP   = 256;   // rotation pairs
constexpr int S    = 8;     // row slices
constexpr int NG   = 32;    // batch groups
constexpr int NB   = 16;    // batches per block
constexpr int ROWS = 64;    // A rows per slice
constexpr int NBLK = NG * S;              // 256 blocks
constexpr int ZROW = 516;   // 512 + 4 pad floats; 516%32==4 -> <=2-way banks
constexpr size_t CNT_BYTES  = 4096;
constexpr size_t PART_BYTES = (size_t)2 * NG * S * NB * 2 * sizeof(float);
}

struct __align__(16) Shm {
    float  zx[NB][ZROW];      // full rotated latent per batch      33024 B
    float2 dpi[NB][NT];       // dx_pi preload                      16384 B
    float  ztile[NB][ROWS];   // staged z slice for coalesced store  4096 B
    float2 om[KP];            // omega                               2048 B
    float2 v[KP];             // normalized z0_base pairs            2048 B
    float2 x[NB];             // current x (redundant per group)
    float2 dt[NB];            // dx_total this step
    float  red[16][NB][2];    // per-wave grad partials              2048 B
    float  nred[16];
    float  pad[8192];         // push LDS past 80 KB -> 1 block/CU  32768 B
};

__global__ __launch_bounds__(1024) void can_main(
    const float* __restrict__ dx_pi, const float* __restrict__ z0,
    const float* __restrict__ x0, const float* __restrict__ omega,
    const float* __restrict__ A, const float* __restrict__ z0b,
    float* __restrict__ d_out,
    unsigned* __restrict__ cnt, float* __restrict__ part)
{
    __shared__ Shm sh;
    const int tid = threadIdx.x;
    const int s   = blockIdx.x & (S - 1);   // row slice (== XCD under %8 rr)
    const int g   = blockIdx.x >> 3;        // batch group
    const int b0  = NB * g;

    float* z_seq = d_out;
    float* x_seq = d_out + (size_t)512 * NT * D;

    if (dx_pi == nullptr) ((volatile float*)sh.pad)[0] = 1.f;  // keep pad live

    // ---- preloads ----
    {
        const float2* dp = reinterpret_cast<const float2*>(dx_pi);
        #pragma unroll
        for (int it = 0; it < 2; ++it) {
            int idx = tid + (it << 10);
            int bb = idx >> 7, tt = idx & 127;
            sh.dpi[bb][tt] = dp[(size_t)(b0 + bb) * NT + tt];
        }
    }
    if (tid < KP) sh.om[tid] = reinterpret_cast<const float2*>(omega)[tid];
    if (tid < NB) sh.x[tid] = reinterpret_cast<const float2*>(x0)[b0 + tid];

    // ---- ||z0_base|| (rotation-invariant, normalize once) ----
    float sq = 0.f;
    if (tid < D) { float f = z0b[tid]; sq = f * f; }
    #pragma unroll
    for (int o = 1; o < 64; o <<= 1) sq += __shfl_xor(sq, o, 64);
    if ((tid & 63) == 0) sh.nred[tid >> 6] = sq;
    __syncthreads();
    float nsq = 0.f;
    #pragma unroll
    for (int w = 0; w < 16; ++w) nsq += sh.nred[w];
    const float zinv = 1.0f / (sqrtf(nsq) + 1e-5f);
    if (tid < KP) {
        float2 vv = reinterpret_cast<const float2*>(z0b)[tid];
        sh.v[tid] = make_float2(vv.x * zinv, vv.y * zinv);
    }

    // ---- persistent carry-z slice: tid<512 owns (pair kk=tid>>4, b=tid&15)
    float zc0 = 0.f, zc1 = 0.f;
    if (tid < 512) {
        int kk = tid >> 4, b = tid & 15;
        float2 z2 = reinterpret_cast<const float2*>(z0)
                        [(size_t)(b0 + b) * KP + 32 * s + kk];
        zc0 = z2.x; zc1 = z2.y;
    }

    // ---- matvec identity: thread = (row r = tid>>4 of slice, batch bm=tid&15)
    const int r  = tid >> 4;
    const int bm = tid & 15;
    const float4* Ap   = reinterpret_cast<const float4*>(A)
                         + (size_t)(ROWS * s + r) * (D / 4);
    const float4* zrow = reinterpret_cast<const float4*>(&sh.zx[bm][0]);

    unsigned target = 0;
    __syncthreads();

    for (int t = 0; t < NT; ++t) {
        // (1) zx = T(omega@x) z0hat for all 16 batches (redundant per group)
        {
            float2 xb = sh.x[bm];
            #pragma unroll
            for (int it = 0; it < 4; ++it) {
                int k = (tid >> 4) + (it << 6);
                float2 o2 = sh.om[k];
                float2 vv = sh.v[k];
                float th = o2.x * xb.x + o2.y * xb.y;
                float sn, cs;
                __sincosf(th, &sn, &cs);
                *reinterpret_cast<float2*>(&sh.zx[bm][2 * k]) =
                    make_float2(cs * vv.x - sn * vv.y, sn * vv.x + cs * vv.y);
            }
        }
        __syncthreads();

        // (2) w[64s+r][bm] = A-row dot zx  (128 KB A slice from L2, 16x reuse)
        float4 acc = {0.f, 0.f, 0.f, 0.f};
        #pragma unroll 8
        for (int i = 0; i < 128; ++i) {
            float4 a = Ap[i];
            float4 z = zrow[i];
            acc.x = fmaf(a.x, z.x, acc.x);
            acc.y = fmaf(a.y, z.y, acc.y);
            acc.z = fmaf(a.z, z.z, acc.z);
            acc.w = fmaf(a.w, z.w, acc.w);
        }
        float w = (acc.x + acc.y) + (acc.z + acc.w);

        // (3) pair rows into g_k = w_odd*zx_even - w_even*zx_odd, wave-reduce
        float wp = __shfl_xor(w, 16, 64);      // partner row r^1 (lane ^16)
        float d0, d1;
        {
            int kk = r >> 1;
            float2 zp = *reinterpret_cast<const float2*>(
                            &sh.zx[bm][64 * s + 2 * kk]);
            float gk = wp * zp.x - w * zp.y;   // valid on even r
            float2 o2 = sh.om[32 * s + kk];
            d0 = gk * o2.x; d1 = gk * o2.y;
            if (r & 1) { d0 = 0.f; d1 = 0.f; }
        }
        d0 += __shfl_xor(d0, 16, 64);
        d1 += __shfl_xor(d1, 16, 64);
        d0 += __shfl_xor(d0, 32, 64);
        d1 += __shfl_xor(d1, 32, 64);
        if ((tid & 63) < 16)
            *reinterpret_cast<float2*>(&sh.red[tid >> 6][tid & 15][0]) =
                make_float2(d0, d1);
        __syncthreads();

        // (4) fold 16 waves -> publish this slice's partial (agent scope)
        float* pbase = part + ((size_t)(t & 1) * NG + g) * (S * NB * 2);
        if (tid < 32) {
            int b = tid >> 1, c = tid & 1;
            float ssum = 0.f;
            #pragma unroll
            for (int w2 = 0; w2 < 16; ++w2) ssum += sh.red[w2][b][c];
            __hip_atomic_store(pbase + (s * NB + b) * 2 + c, ssum,
                               __ATOMIC_RELAXED, __HIP_MEMORY_SCOPE_AGENT);
        }

        // (5) 8-block group barrier: release on arrive, acquire on spin.
        //     Monotone counter (zeroed by the captured memset each launch).
        target += S;
        if (tid == 0) {
            __hip_atomic_fetch_add(&cnt[g * 32], 1u,
                                   __ATOMIC_RELEASE, __HIP_MEMORY_SCOPE_AGENT);
            while (__hip_atomic_load(&cnt[g * 32],
                                     __ATOMIC_ACQUIRE, __HIP_MEMORY_SCOPE_AGENT)
                   < target)
                __builtin_amdgcn_s_sleep(2);
        }
        __syncthreads();

        // (6) sum the 8 slice partials -> dx_total; update x (all 8 blocks
        //     compute bitwise-identical sums -> consistent redundant state)
        if (tid < 32) {
            int b = tid >> 1, c = tid & 1;
            float ssum = 0.f;
            #pragma unroll
            for (int sl = 0; sl < S; ++sl)
                ssum += __hip_atomic_load(pbase + (sl * NB + b) * 2 + c,
                                          __ATOMIC_RELAXED,
                                          __HIP_MEMORY_SCOPE_AGENT);
            float pi  = c ? sh.dpi[b][t].y : sh.dpi[b][t].x;
            float dtv = pi + 0.1f * ssum;
            reinterpret_cast<float*>(&sh.dt[b])[c] = dtv;
            float xv = c ? sh.x[b].y : sh.x[b].x;
            xv = fminf(fmaxf(xv + dtv, 0.f), 2.0f);
            reinterpret_cast<float*>(&sh.x[b])[c] = xv;
        }
        __syncthreads();

        // (7) rotate carry-z slice, stage to LDS; slice 0 stores x_seq
        if (tid < 512) {
            int kk = tid >> 4, b = tid & 15;
            float2 dtv = sh.dt[b];
            float2 o2  = sh.om[32 * s + kk];
            float th = o2.x * dtv.x + o2.y * dtv.y;
            float sn, cs;
            __sincosf(th, &sn, &cs);
            float n0 = cs * zc0 - sn * zc1;
            float n1 = sn * zc0 + cs * zc1;
            zc0 = n0; zc1 = n1;
            *reinterpret_cast<float2*>(&sh.ztile[b][2 * kk]) =
                make_float2(n0, n1);
        } else if (s == 0 && tid < 512 + NB) {
            int b = tid - 512;
            reinterpret_cast<float2*>(x_seq)[(size_t)(b0 + b) * NT + t] =
                sh.x[b];
        }
        __syncthreads();

        // (8) coalesced z_seq store (nontemporal: keep L2 clean so the
        //     barrier's release writeback has ~nothing to flush)
        {
            int b = tid >> 6, dl = tid & 63;
            __builtin_nontemporal_store(
                sh.ztile[b][dl],
                &z_seq[((size_t)(b0 + b) * NT + t) * D + ROWS * s + dl]);
        }
        // no barrier: next phase (1) touches only zx/x, both quiescent here
    }
}

extern "C" void kernel_launch(void* const* d_in, const int* in_sizes, int n_in,
                              void* d_out, int out_size, void* d_ws, size_t ws_size,
                              hipStream_t stream) {
    (void)in_sizes; (void)n_in; (void)out_size; (void)ws_size;
    unsigned* cnt = reinterpret_cast<unsigned*>(d_ws);
    float* part = reinterpret_cast<float*>(reinterpret_cast<char*>(d_ws) + CNT_BYTES);
    (void)PART_BYTES;
    hipMemsetAsync(d_ws, 0, CNT_BYTES, stream);   // zero barrier counters
    hipLaunchKernelGGL(can_main, dim3(NBLK), dim3(1024), 0, stream,
                       (const float*)d_in[0], (const float*)d_in[1],
                       (const float*)d_in[2], (const float*)d_in[3],
                       (const float*)d_in[4], (const float*)d_in[5],
                       (float*)d_out, cnt, part);
}

// Round 2
// 956.472 us; speedup vs baseline: 2.5386x; 2.5386x over previous
//
#include <hip/hip_runtime.h>

// CANPathIntegrator — R7: serial/parallel factorization + 4-slice matvec.
//
// Key algebra: block-diagonal rotations commute, so the carried latent is
// z_t = R(omega @ S_t) z0 with S_t = cumsum(dx_total). The chaotic part of
// the recurrence is ONLY x_t (needs dx_can(x_t) = bilinear form through
// w = A zx). So:
//   Kernel 1 (can_serial, 256 blocks = 64 groups x 4 slices): runs the
//     x-recurrence. Each block streams a 256KB A-slice from L2 per step
//     (per-CU L2 port ~64B/cyc was R5's 6.8us/step limiter; now 1.7us,
//     balanced vs 1.7us FMA) and contracts its partial w against
//     xi (dx = sum_c w[c] xi_c is linear in w -> slices exchange only
//     2 floats/batch/step). Exchange via agent-scope (MALL-coherent sc1)
//     atomics, RELAXED spin (R6 post-mortem: acquire-loads invalidate L2
//     every poll -> 24MB refetch + huge latency). __syncthreads' implicit
//     vmcnt(0) is the release drain. 100KB LDS forces 1 block/CU, grid
//     == 256 CUs -> all groups resident, spin cannot deadlock.
//   Kernel 2 (can_zrot, 512 blocks): z_seq[b][t] = R(omega@S_t) z0[b],
//     fully parallel, HBM-write-bound (~25us). S_t is stashed by kernel 1
//     in z_seq[b][t][0:2] and read back before overwrite.

namespace {
constexpr int NT  = 128;   // time steps
constexpr int DD  = 512;   // latent dim
constexpr int KP  = 256;   // rotation pairs
constexpr int NS  = 4;     // row slices per group (128 rows each)
constexpr int NG  = 64;    // batch groups
constexpr int NB  = 8;     // batches per group
constexpr int ZST = 12;    // dwords per zx row: 8 data + 4 pad (bank spread)
constexpr size_t CNT_BYTES = 8192;   // 64 groups x 128B counter lines
}

struct ShmA {
    float  zx[DD * ZST];        // 24 KB  row c at dword ZST*c, +b for batch b
    float  wpart[4][NB][DD];    // 64 KB  [row-chunk rq][b][c] partial w
    float2 dpi[NB][NT];         //  8 KB  dx_pi preload
    float2 om[KP];              //  2 KB
    float2 v[KP];               //  2 KB  normalized z0_base pairs
    float2 x[NB];               // current x (redundant per slice, identical)
    float  nred[16];
};

__global__ __launch_bounds__(1024) void can_serial(
    const float* __restrict__ dx_pi, const float* __restrict__ x0,
    const float* __restrict__ omega, const float* __restrict__ A,
    const float* __restrict__ z0b, float* __restrict__ d_out,
    unsigned* __restrict__ cnt, float* __restrict__ part)
{
    __shared__ ShmA sh;
    const int tid = threadIdx.x;
    const int g   = blockIdx.x >> 2;    // batch group
    const int s   = blockIdx.x & 3;     // row slice: rows 128s..128s+127
    const int b0  = NB * g;

    float* z_seq = d_out;
    float* x_seq = d_out + (size_t)512 * NT * DD;

    // ---- preloads ----
    {
        int bb = tid >> 7, tt = tid & 127;     // exactly 1024 threads
        sh.dpi[bb][tt] =
            reinterpret_cast<const float2*>(dx_pi)[(size_t)(b0 + bb) * NT + tt];
    }
    if (tid < KP) sh.om[tid] = reinterpret_cast<const float2*>(omega)[tid];

    // ||z0_base|| (rotation-invariant -> normalize once)
    float sq = 0.f;
    if (tid < DD) { float f = z0b[tid]; sq = f * f; }
    #pragma unroll
    for (int o = 1; o < 64; o <<= 1) sq += __shfl_xor(sq, o, 64);
    if ((tid & 63) == 0) sh.nred[tid >> 6] = sq;
    __syncthreads();
    float nsq = 0.f;
    #pragma unroll
    for (int w = 0; w < 16; ++w) nsq += sh.nred[w];
    const float zinv = 1.0f / (sqrtf(nsq) + 1e-5f);
    if (tid < KP) {
        float2 vv = reinterpret_cast<const float2*>(z0b)[tid];
        sh.v[tid] = make_float2(vv.x * zinv, vv.y * zinv);
    }

    // persistent x / S state in threads 0..15 (b = tid>>1, comp = tid&1)
    float xreg = 0.f, Sreg = 0.f;
    if (tid < 2 * NB) {
        xreg = x0[(size_t)(b0 + (tid >> 1)) * 2 + (tid & 1)];
        reinterpret_cast<float*>(&sh.x[tid >> 1])[tid & 1] = xreg;
    }
    __syncthreads();

    // role constants
    const int rq = tid >> 8;        // P2: row chunk (32 rows) within slice
    const int p2 = tid & 255;       // P2: float2 col pair (cols 2p2, 2p2+1)
    const float2* A2 = reinterpret_cast<const float2*>(A)
                       + (size_t)(128 * s + 32 * rq) * 256 + p2;
    const int k1 = tid >> 2;        // P1: pair index
    const int bq = tid & 3;         // P1: batch pair (2bq, 2bq+1)
    const int b3 = tid >> 7;        // P3: batch
    const int cc = tid & 127;       // P3: col residue (c = cc + 128m)
    const int wv = tid >> 6;        // wave index

    unsigned* mycnt = cnt + g * 32;

    for (int t = 0; t < NT; ++t) {
        // ---- P1: zx[c][b] = T(omega@x_b) z0hat, all 8 batches ----
        {
            float2 o2 = sh.om[k1];
            float2 vv = sh.v[k1];
            #pragma unroll
            for (int j = 0; j < 2; ++j) {
                int b = 2 * bq + j;
                float2 xb = sh.x[b];
                float th = o2.x * xb.x + o2.y * xb.y;
                float sn, cs;
                __sincosf(th, &sn, &cs);
                sh.zx[ZST * (2 * k1)     + b] = cs * vv.x - sn * vv.y;
                sh.zx[ZST * (2 * k1 + 1) + b] = sn * vv.x + cs * vv.y;
            }
        }
        __syncthreads();

        // ---- P2: slice matvec partials, w'[c][b] += A[r][c] * zx[r][b]
        //      (A symmetric -> column-order evaluation, coalesced rows) ----
        {
            float a0[NB] = {}, a1[NB] = {};
            const int rbase = ZST * (128 * s + 32 * rq);
            #pragma unroll 8
            for (int jj = 0; jj < 32; ++jj) {
                float2 av = A2[(size_t)jj * 256];
                const float* zr = &sh.zx[rbase + ZST * jj];
                float4 z0v = *reinterpret_cast<const float4*>(zr);      // b0..3
                float4 z1v = *reinterpret_cast<const float4*>(zr + 4);  // b4..7
                a0[0] = fmaf(av.x, z0v.x, a0[0]); a1[0] = fmaf(av.y, z0v.x, a1[0]);
                a0[1] = fmaf(av.x, z0v.y, a0[1]); a1[1] = fmaf(av.y, z0v.y, a1[1]);
                a0[2] = fmaf(av.x, z0v.z, a0[2]); a1[2] = fmaf(av.y, z0v.z, a1[2]);
                a0[3] = fmaf(av.x, z0v.w, a0[3]); a1[3] = fmaf(av.y, z0v.w, a1[3]);
                a0[4] = fmaf(av.x, z1v.x, a0[4]); a1[4] = fmaf(av.y, z1v.x, a1[4]);
                a0[5] = fmaf(av.x, z1v.y, a0[5]); a1[5] = fmaf(av.y, z1v.y, a1[5]);
                a0[6] = fmaf(av.x, z1v.z, a0[6]); a1[6] = fmaf(av.y, z1v.z, a1[6]);
                a0[7] = fmaf(av.x, z1v.w, a0[7]); a1[7] = fmaf(av.y, z1v.w, a1[7]);
            }
            #pragma unroll
            for (int b = 0; b < NB; ++b)
                *reinterpret_cast<float2*>(&sh.wpart[rq][b][2 * p2]) =
                    make_float2(a0[b], a1[b]);
        }
        __syncthreads();

        // ---- P3: fold chunks + xi-contract + wave-reduce + publish ----
        // dx_partial = sum_c w_slice[c] * xi_c,  xi_{2k}=-zx[2k+1]*om_k,
        // xi_{2k+1}=+zx[2k]*om_k  (linear in w -> slices sum later)
        {
            float d0 = 0.f, d1 = 0.f;
            #pragma unroll
            for (int m = 0; m < 4; ++m) {
                int c = cc + 128 * m;
                float wvv = sh.wpart[0][b3][c] + sh.wpart[1][b3][c]
                          + sh.wpart[2][b3][c] + sh.wpart[3][b3][c];
                float zp = sh.zx[ZST * (c ^ 1) + b3];
                float2 o2 = sh.om[c >> 1];
                float tt = wvv * zp;
                tt = (c & 1) ? tt : -tt;
                d0 = fmaf(tt, o2.x, d0);
                d1 = fmaf(tt, o2.y, d1);
            }
            #pragma unroll
            for (int o = 1; o < 64; o <<= 1) {
                d0 += __shfl_xor(d0, o, 64);
                d1 += __shfl_xor(d1, o, 64);
            }
            if ((tid & 63) == 0) {   // one publish per wave: [b3][wave-half]
                float* pb = part +
                    ((((size_t)(t & 1) * NG + g) * NS + s) * NB + b3) * 4 +
                    (wv & 1) * 2;
                __hip_atomic_store(pb,     d0, __ATOMIC_RELAXED,
                                   __HIP_MEMORY_SCOPE_AGENT);
                __hip_atomic_store(pb + 1, d1, __ATOMIC_RELAXED,
                                   __HIP_MEMORY_SCOPE_AGENT);
            }
        }
        __syncthreads();   // implicit vmcnt(0): all publishes MALL-acked

        // ---- group barrier: monotone counter at MALL, relaxed spin ----
        if (tid == 0) {
            __atomic_signal_fence(__ATOMIC_SEQ_CST);
            __hip_atomic_fetch_add(mycnt, 1u, __ATOMIC_RELAXED,
                                   __HIP_MEMORY_SCOPE_AGENT);
            const unsigned tgt = (unsigned)NS * (unsigned)(t + 1);
            while (__hip_atomic_load(mycnt, __ATOMIC_RELAXED,
                                     __HIP_MEMORY_SCOPE_AGENT) < tgt)
                __builtin_amdgcn_s_sleep(1);
            __atomic_signal_fence(__ATOMIC_SEQ_CST);
        }
        __syncthreads();

        // ---- P4: sum 4 slices x 2 halves -> dx_total; update x, S ----
        if (tid < 2 * NB) {
            int b = tid >> 1, c4 = tid & 1;
            float ssum = 0.f;
            #pragma unroll
            for (int sl = 0; sl < NS; ++sl) {
                const float* pr = part +
                    ((((size_t)(t & 1) * NG + g) * NS + sl) * NB + b) * 4 + c4;
                ssum += __hip_atomic_load(pr,     __ATOMIC_RELAXED,
                                          __HIP_MEMORY_SCOPE_AGENT);
                ssum += __hip_atomic_load(pr + 2, __ATOMIC_RELAXED,
                                          __HIP_MEMORY_SCOPE_AGENT);
            }
            float pi = reinterpret_cast<const float*>(&sh.dpi[b][t])[c4];
            float dtv = fmaf(0.1f, ssum, pi);
            Sreg += dtv;                                   // unclipped cumsum
            xreg = fminf(fmaxf(xreg + dtv, 0.f), 2.0f);    // clipped x
            reinterpret_cast<float*>(&sh.x[b])[c4] = xreg;
            if (s == 0) {
                x_seq[((size_t)(b0 + b) * NT + t) * 2 + c4] = xreg;
                z_seq[((size_t)(b0 + b) * NT + t) * DD + c4] = Sreg;  // stash
            }
        }
        __syncthreads();
    }
}

// ---- Kernel 2: z_seq[b][t] = R(omega @ S_t) z0[b], fully parallel ----
struct ShmB { float2 zp[KP]; float2 om[KP]; float2 Sv[NT]; };

__global__ __launch_bounds__(256) void can_zrot(
    const float* __restrict__ z0, const float* __restrict__ omega,
    float* __restrict__ d_out)
{
    __shared__ ShmB sh;
    const int b = blockIdx.x;
    const int tid = threadIdx.x;
    float* z_seq = d_out;

    sh.zp[tid] = reinterpret_cast<const float2*>(z0)[(size_t)b * KP + tid];
    sh.om[tid] = reinterpret_cast<const float2*>(omega)[tid];
    if (tid < NT)   // read S stash BEFORE the t-loop overwrites [t][0:2]
        sh.Sv[tid] = *reinterpret_cast<const float2*>(
            &z_seq[((size_t)b * NT + tid) * DD]);
    __syncthreads();

    const float2 zp = sh.zp[tid];
    const float2 o2 = sh.om[tid];
    float2* out = reinterpret_cast<float2*>(z_seq) + (size_t)b * NT * KP + tid;
    for (int t = 0; t < NT; ++t) {
        float2 S = sh.Sv[t];
        float th = o2.x * S.x + o2.y * S.y;
        float sn, cs;
        __sincosf(th, &sn, &cs);
        out[(size_t)t * KP] =
            make_float2(cs * zp.x - sn * zp.y, sn * zp.x + cs * zp.y);
    }
}

extern "C" void kernel_launch(void* const* d_in, const int* in_sizes, int n_in,
                              void* d_out, int out_size, void* d_ws, size_t ws_size,
                              hipStream_t stream) {
    (void)in_sizes; (void)n_in; (void)out_size; (void)ws_size;
    unsigned* cnt = reinterpret_cast<unsigned*>(d_ws);
    float* part = reinterpret_cast<float*>(reinterpret_cast<char*>(d_ws) + CNT_BYTES);
    hipMemsetAsync(d_ws, 0, CNT_BYTES, stream);   // zero group counters
    hipLaunchKernelGGL(can_serial, dim3(NG * NS), dim3(1024), 0, stream,
                       (const float*)d_in[0], (const float*)d_in[2],
                       (const float*)d_in[3], (const float*)d_in[4],
                       (const float*)d_in[5], (float*)d_out, cnt, part);
    hipLaunchKernelGGL(can_zrot, dim3(512), dim3(256), 0, stream,
                       (const float*)d_in[1], (const float*)d_in[3],
                       (float*)d_out);
}